// Round 8
// baseline (728.694 us; speedup 1.0000x reference)
//
#include <hip/hip_runtime.h>
#include <cstdint>
#include <cstddef>

// One wave (64 lanes) per batch (B=4096, N=K=64); 4 independent waves per
// 256-thread block. Zero __shared__, zero barriers.
// R8 structural change: COLUMN-ONLY storage (col[64], lane j holds X0[:,j]).
// Row phase r_i = sum_j X0[i][j]*v_j is computed from col layout with a
// 6-stage butterfly reduce-scatter (shfl_xor masks 32..1): lane j forms
// col[i]*v_j locally (v lane-local, NO broadcast), tree-sum delivers r_i to
// lane i. This kills the row2[64] register array that pushed the live set to
// ~200 unified regs (AGPR overflow -> accvgpr moves ~2x'd VALU count and
// capped residency at 2 waves/SIMD). Col phase + epilogue + greedy are the
// R5/R7-verified code verbatim (exact chunk-4 order, readlane broadcasts).

__device__ __forceinline__ float rl(float x, int lane) {
    return __uint_as_float((unsigned)__builtin_amdgcn_readlane((int)__float_as_uint(x), lane));
}

#define RESCAN(G)                                                            \
  {                                                                          \
    float nv_ = -__builtin_inff(); int na_ = (G) * 8;                        \
    _Pragma("unroll")                                                        \
    for (int k_ = 0; k_ < 8; ++k_) {                                         \
      const int idx_ = (G) * 8 + k_;                                         \
      float vk_ = ((rowmask >> idx_) & 1ull) ? col[idx_]                     \
                                             : -__builtin_inff();            \
      if (vk_ > nv_) { nv_ = vk_; na_ = idx_; }                              \
    }                                                                        \
    gv[(G)] = nv_; ga[(G)] = na_;                                            \
  }

#define RESCAN_SWITCH(RG)                                                    \
    switch (RG) {                                                            \
        case 0: RESCAN(0) break;                                             \
        case 1: RESCAN(1) break;                                             \
        case 2: RESCAN(2) break;                                             \
        case 3: RESCAN(3) break;                                             \
        case 4: RESCAN(4) break;                                             \
        case 5: RESCAN(5) break;                                             \
        case 6: RESCAN(6) break;                                             \
        case 7: RESCAN(7) break;                                             \
    }

__global__ void __launch_bounds__(256)
sinkhorn_perm_kernel(const float* __restrict__ logits,
                     const float* __restrict__ ptemp,
                     float* __restrict__ out, int B)
{
    const int wid  = threadIdx.x >> 6;
    const int lane = threadIdx.x & 63;
    const int b    = blockIdx.x * 4 + wid;
    if (b >= B) return;               // no barriers/LDS anywhere: safe exit

    const float* base = logits + (size_t)b * 4096;

    const float T    = ptemp[0] + 1e-6f;
    const float invT = 1.0f / T;          // IEEE divide (one-time)

    // ---- column-layout load (coalesced across lanes), scale by invT ---
    float col[64];
    #pragma unroll
    for (int i = 0; i < 64; ++i)
        col[i] = __fmul_rn(base[i * 64 + lane], invT);

    // ---- global max over the 64x64 tile (max is order-exact) ----------
    float mx = col[0];
    #pragma unroll
    for (int i = 1; i < 64; ++i) mx = fmaxf(mx, col[i]);
    #pragma unroll
    for (int w = 1; w <= 32; w <<= 1)
        mx = fmaxf(mx, __shfl_xor(mx, w, 64));

    // ---- x0 column copy: exp(scaled - mx) -----------------------------
    #pragma unroll
    for (int i = 0; i < 64; ++i)
        col[i] = __expf(__fsub_rn(col[i], mx));

    // ---- sinkhorn in diag(u) * X0 * diag(v) form ----------------------
    // u_i lives on lane i; v_j lives on lane j.
    float u = 1.0f, v = 1.0f;
    for (int it = 0; it < 30; ++it) {
        // row phase: r_i = sum_j X0[i][j]*v_j via butterfly reduce-scatter.
        // Lane j's local products col[i]*v need no broadcast (v lane-local);
        // stage mask m keeps the half of indices whose bit matches lane's.
        float t[32];
        {
            const bool h32 = (lane & 32) != 0;
            #pragma unroll
            for (int s = 0; s < 32; ++s) {
                float plo = __fmul_rn(col[s],      v);
                float phi = __fmul_rn(col[s + 32], v);
                float olo = __shfl_xor(plo, 32, 64);
                float ohi = __shfl_xor(phi, 32, 64);
                t[s] = __fadd_rn(h32 ? phi : plo, h32 ? ohi : olo);
            }
        }
        #pragma unroll
        for (int m = 16; m >= 1; m >>= 1) {
            const bool hm = (lane & m) != 0;
            #pragma unroll
            for (int s = 0; s < m; ++s) {
                float a   = hm ? t[s + m] : t[s];
                float olo = __shfl_xor(t[s],     m, 64);
                float ohi = __shfl_xor(t[s + m], m, 64);
                t[s] = __fadd_rn(a, hm ? ohi : olo);
            }
        }
        float r = t[0];                               // r_{lane}
        u = u / __fadd_rn(__fmul_rn(u, r), 1e-8f);    // IEEE divide

        // col phase: c_j = sum_i col_j[i]*u_i  (exact chunk-4, R5 verbatim)
        float a0 = 0.f, a1 = 0.f, a2 = 0.f, a3 = 0.f;
        #pragma unroll
        for (int i = 0; i < 64; i += 4) {
            a0 = __builtin_fmaf(col[i+0], rl(u, i+0), a0);
            a1 = __builtin_fmaf(col[i+1], rl(u, i+1), a1);
            a2 = __builtin_fmaf(col[i+2], rl(u, i+2), a2);
            a3 = __builtin_fmaf(col[i+3], rl(u, i+3), a3);
        }
        float cs = __fadd_rn(__fadd_rn(a0, a1), __fadd_rn(a2, a3));
        v = v / __fadd_rn(__fmul_rn(v, cs), 1e-8f);
    }

    // ---- final scores: s[i][j] = (x0[i][j] * u_i) * v_j ---------------
    #pragma unroll
    for (int i = 0; i < 64; ++i)
        col[i] = __fmul_rn(__fmul_rn(col[i], rl(u, i)), v);

    // ---- greedy unique argmax (verified: top-2 fast path + fallback) --
    unsigned long long rowmask = ~0ull;   // wave-uniform (SGPR pair)
    float gv[8]; int ga[8];
    #pragma unroll
    for (int g = 0; g < 8; ++g) RESCAN(g)

    int  mycol   = 0;
    bool done    = false;
    int  retired = 0;
    const float NEGINF = -__builtin_inff();

    while (retired < 64) {
        // per-lane best over 8 groups (ascending + strict '>' => min row on tie)
        float bv = gv[0]; int ba = ga[0];
        #pragma unroll
        for (int g2 = 1; g2 < 8; ++g2)
            if (gv[g2] > bv) { bv = gv[g2]; ba = ga[g2]; }
        float mybv = done ? NEGINF : bv;

        // wave-wide top-2 values (butterfly; disjoint-group merge each stage)
        float m1 = mybv, m2 = NEGINF;
        #pragma unroll
        for (int m = 1; m <= 32; m <<= 1) {
            float o1 = __shfl_xor(m1, m, 64);
            float o2 = __shfl_xor(m2, m, 64);
            float hi = fmaxf(m1, o1);
            float lo = fminf(m1, o1);
            m1 = hi;
            m2 = fmaxf(lo, fmaxf(m2, o2));
        }

        int r1, c1, r2 = -1, c2 = -1;
        bool two = false;
        unsigned long long t1 = __ballot(mybv == m1);   // wave-uniform
        bool fast1 = (__popcll(t1) == 1) && (m2 > NEGINF);

        if (fast1) {
            c1 = (int)__builtin_ctzll(t1);
            r1 = __builtin_amdgcn_readlane(ba, c1);
            unsigned long long t2 = __ballot(mybv == m2);
            if (__popcll(t2) == 1) {
                c2 = (int)__builtin_ctzll(t2);
                r2 = __builtin_amdgcn_readlane(ba, c2);
                two = (r2 != r1);
            }
        } else {
            // fallback: verified u64-key single retirement
            unsigned flat = ((unsigned)ba << 6) | (unsigned)lane;   // r*64 + c
            unsigned long long key =
                ((unsigned long long)__float_as_uint(bv) << 12) | (4095u - flat);
            if (done) key = 0ull;
            #pragma unroll
            for (int m = 1; m <= 32; m <<= 1) {
                unsigned long long o = __shfl_xor(key, m, 64);
                if (o > key) key = o;
            }
            unsigned wflat = 4095u - (unsigned)(key & 4095ull);
            r1 = __builtin_amdgcn_readfirstlane((int)(wflat >> 6));
            c1 = (int)(wflat & 63u);
        }

        // retire (r1,c1) [and (r2,c2)]
        if (lane == r1) mycol = c1;
        if (lane == c1) done  = true;
        rowmask &= ~(1ull << r1);
        retired++;
        if (two) {
            if (lane == r2) mycol = c2;
            if (lane == c2) done  = true;
            rowmask &= ~(1ull << r2);
            retired++;
        }

        // rescan affected group(s); (r>>3) is wave-uniform
        RESCAN_SWITCH(r1 >> 3)
        if (two && ((r2 >> 3) != (r1 >> 3))) {
            RESCAN_SWITCH(r2 >> 3)
        }
    }

    // ---- write hard permutation row (lane i -> row i) -----------------
    float* orow = out + (size_t)b * 4096 + lane * 64;
    #pragma unroll
    for (int t2 = 0; t2 < 16; ++t2) {
        float4 q;
        q.x = (4*t2+0 == mycol) ? 1.0f : 0.0f;
        q.y = (4*t2+1 == mycol) ? 1.0f : 0.0f;
        q.z = (4*t2+2 == mycol) ? 1.0f : 0.0f;
        q.w = (4*t2+3 == mycol) ? 1.0f : 0.0f;
        ((float4*)orow)[t2] = q;
    }
}

extern "C" void kernel_launch(void* const* d_in, const int* in_sizes, int n_in,
                              void* d_out, int out_size, void* d_ws, size_t ws_size,
                              hipStream_t stream) {
    const float* logits = (const float*)d_in[0];
    const float* ptemp  = (const float*)d_in[1];
    float* out = (float*)d_out;
    const int B = in_sizes[0] / 4096;   // 64*64 elements per batch
    sinkhorn_perm_kernel<<<(B + 3) / 4, 256, 0, stream>>>(logits, ptemp, out, B);
}

// Round 9
// 252.043 us; speedup vs baseline: 2.8911x; 2.8911x over previous
//
#include <hip/hip_runtime.h>
#include <cstdint>
#include <cstddef>

// WAVE-SPECIALIZED pair per batch (B=4096, N=K=64):
//   wave A (role 0) holds the ROW copy of X0 (mat[64] = row `lane`)
//   wave B (role 1) holds the COL copy of X0 (mat[64] = column `lane`)
// Each wave stores ONE 64-float array -> live set ~90 floats, fits the arch
// VGPR budget with no AGPR overflow (R5-R7 kept row+col = 128 floats in one
// wave; LLVM parked the overflow in AGPRs -> accvgpr moves ~2x'd VALU count
// and pinned true residency at 2 waves/SIMD on the unified gfx950 RF).
// Per sinkhorn half-iteration the pair exchanges the 64-float u/v vector
// through LDS (1 ds_write + 1 ds_read per lane + 2 barriers) — negligible
// DS traffic (R8's shuffle storm was the opposite mistake).
// All arithmetic is R5-verbatim: chunk-4 fma dots with readlane broadcasts,
// IEEE divides, identical epilogue and greedy (top-2 fast path + u64-key
// fallback). LDS round-trips are bit-exact copies -> absmax 0 expected.
// Block = 256 threads = 2 independent pairs = 2 batches; grid = B/2.

__device__ __forceinline__ float rl(float x, int lane) {
    return __uint_as_float((unsigned)__builtin_amdgcn_readlane((int)__float_as_uint(x), lane));
}

#define RESCAN(G)                                                            \
  {                                                                          \
    float nv_ = -__builtin_inff(); int na_ = (G) * 8;                        \
    _Pragma("unroll")                                                        \
    for (int k_ = 0; k_ < 8; ++k_) {                                         \
      const int idx_ = (G) * 8 + k_;                                         \
      float vk_ = ((rowmask >> idx_) & 1ull) ? mat[idx_]                     \
                                             : -__builtin_inff();            \
      if (vk_ > nv_) { nv_ = vk_; na_ = idx_; }                              \
    }                                                                        \
    gv[(G)] = nv_; ga[(G)] = na_;                                            \
  }

#define RESCAN_SWITCH(RG)                                                    \
    switch (RG) {                                                            \
        case 0: RESCAN(0) break;                                             \
        case 1: RESCAN(1) break;                                             \
        case 2: RESCAN(2) break;                                             \
        case 3: RESCAN(3) break;                                             \
        case 4: RESCAN(4) break;                                             \
        case 5: RESCAN(5) break;                                             \
        case 6: RESCAN(6) break;                                             \
        case 7: RESCAN(7) break;                                             \
    }

__global__ void __launch_bounds__(256)
sinkhorn_perm_kernel(const float* __restrict__ logits,
                     const float* __restrict__ ptemp,
                     float* __restrict__ out, int Btot)
{
    const int wid  = threadIdx.x >> 6;   // 0..3
    const int pair = wid >> 1;           // 0..1  (batch within block)
    const int role = wid & 1;            // 0 = row-holder A, 1 = col-holder B
    const int lane = threadIdx.x & 63;
    int b = blockIdx.x * 2 + pair;
    if (b >= Btot) b = Btot - 1;         // duplicate work, identical output

    __shared__ float u_buf[2][64];
    __shared__ float v_buf[2][64];

    const float* base = logits + (size_t)b * 4096;

    const float T    = ptemp[0] + 1e-6f;
    const float invT = 1.0f / T;         // IEEE divide (one-time)

    // ---- load my copy of X0, scaled by invT ---------------------------
    // A: row `lane` (float4, 16B/lane); B: column `lane` (stride-64, coalesced)
    float mat[64];
    if (role == 0) {
        const float4* rp = (const float4*)(base + lane * 64);
        #pragma unroll
        for (int t = 0; t < 16; ++t) {
            float4 q = rp[t];
            mat[4*t+0] = __fmul_rn(q.x, invT);
            mat[4*t+1] = __fmul_rn(q.y, invT);
            mat[4*t+2] = __fmul_rn(q.z, invT);
            mat[4*t+3] = __fmul_rn(q.w, invT);
        }
    } else {
        #pragma unroll
        for (int i = 0; i < 64; ++i)
            mat[i] = __fmul_rn(base[i * 64 + lane], invT);
    }

    // ---- global max over the 64x64 tile (exact, order-free) -----------
    float mx = mat[0];
    #pragma unroll
    for (int i = 1; i < 64; ++i) mx = fmaxf(mx, mat[i]);
    #pragma unroll
    for (int w = 1; w <= 32; w <<= 1)
        mx = fmaxf(mx, __shfl_xor(mx, w, 64));

    // ---- x0 = exp(scaled - mx), identical op sequence both roles ------
    #pragma unroll
    for (int i = 0; i < 64; ++i)
        mat[i] = __expf(__fsub_rn(mat[i], mx));

    // ---- sinkhorn in diag(u) * X0 * diag(v) form ----------------------
    // A keeps u_lane; B keeps v_lane. Exchange via LDS each half-iteration.
    float scal = 1.0f;         // A: u, B: v
    float u_reg = 1.0f;        // B: latest u (for epilogue)
    for (int it = 0; it < 30; ++it) {
        if (role == 0) {
            // row phase: r_i = row_i . v  (v_j broadcast via readlane)
            float vb = (it == 0) ? 1.0f : v_buf[pair][lane];
            float a0 = 0.f, a1 = 0.f, a2 = 0.f, a3 = 0.f;
            #pragma unroll
            for (int j = 0; j < 64; j += 4) {
                a0 = __builtin_fmaf(mat[j+0], rl(vb, j+0), a0);
                a1 = __builtin_fmaf(mat[j+1], rl(vb, j+1), a1);
                a2 = __builtin_fmaf(mat[j+2], rl(vb, j+2), a2);
                a3 = __builtin_fmaf(mat[j+3], rl(vb, j+3), a3);
            }
            float rs = __fadd_rn(__fadd_rn(a0, a1), __fadd_rn(a2, a3));
            scal = scal / __fadd_rn(__fmul_rn(scal, rs), 1e-8f);  // u update
            u_buf[pair][lane] = scal;
        }
        __syncthreads();
        if (role == 1) {
            // col phase: c_j = col_j . u  (u_i broadcast via readlane)
            u_reg = u_buf[pair][lane];
            float a0 = 0.f, a1 = 0.f, a2 = 0.f, a3 = 0.f;
            #pragma unroll
            for (int i = 0; i < 64; i += 4) {
                a0 = __builtin_fmaf(mat[i+0], rl(u_reg, i+0), a0);
                a1 = __builtin_fmaf(mat[i+1], rl(u_reg, i+1), a1);
                a2 = __builtin_fmaf(mat[i+2], rl(u_reg, i+2), a2);
                a3 = __builtin_fmaf(mat[i+3], rl(u_reg, i+3), a3);
            }
            float cs = __fadd_rn(__fadd_rn(a0, a1), __fadd_rn(a2, a3));
            scal = scal / __fadd_rn(__fmul_rn(scal, cs), 1e-8f);  // v update
            v_buf[pair][lane] = scal;
        }
        __syncthreads();
    }

    if (role == 0) return;   // A done (no further barriers anywhere)

    // ================== wave B only: epilogue + greedy ==================
    // final scores: s[i][j] = (x0[i][j] * u_i) * v_j   (scal == final v)
    #pragma unroll
    for (int i = 0; i < 64; ++i)
        mat[i] = __fmul_rn(__fmul_rn(mat[i], rl(u_reg, i)), scal);

    // greedy unique argmax (verified: top-2 fast path + u64-key fallback)
    unsigned long long rowmask = ~0ull;   // wave-uniform (SGPR pair)
    float gv[8]; int ga[8];
    #pragma unroll
    for (int g = 0; g < 8; ++g) RESCAN(g)

    int  mycol   = 0;
    bool done    = false;
    int  retired = 0;
    const float NEGINF = -__builtin_inff();

    while (retired < 64) {
        // per-lane best over 8 groups (ascending + strict '>' => min row on tie)
        float bv = gv[0]; int ba = ga[0];
        #pragma unroll
        for (int g2 = 1; g2 < 8; ++g2)
            if (gv[g2] > bv) { bv = gv[g2]; ba = ga[g2]; }
        float mybv = done ? NEGINF : bv;

        // wave-wide top-2 values (butterfly; disjoint-group merge each stage)
        float m1 = mybv, m2 = NEGINF;
        #pragma unroll
        for (int m = 1; m <= 32; m <<= 1) {
            float o1 = __shfl_xor(m1, m, 64);
            float o2 = __shfl_xor(m2, m, 64);
            float hi = fmaxf(m1, o1);
            float lo = fminf(m1, o1);
            m1 = hi;
            m2 = fmaxf(lo, fmaxf(m2, o2));
        }

        int r1, c1, r2 = -1, c2 = -1;
        bool two = false;
        unsigned long long t1 = __ballot(mybv == m1);   // wave-uniform
        bool fast1 = (__popcll(t1) == 1) && (m2 > NEGINF);

        if (fast1) {
            c1 = (int)__builtin_ctzll(t1);
            r1 = __builtin_amdgcn_readlane(ba, c1);
            unsigned long long t2 = __ballot(mybv == m2);
            if (__popcll(t2) == 1) {
                c2 = (int)__builtin_ctzll(t2);
                r2 = __builtin_amdgcn_readlane(ba, c2);
                two = (r2 != r1);
            }
        } else {
            // fallback: verified u64-key single retirement
            unsigned flat = ((unsigned)ba << 6) | (unsigned)lane;   // r*64 + c
            unsigned long long key =
                ((unsigned long long)__float_as_uint(bv) << 12) | (4095u - flat);
            if (done) key = 0ull;
            #pragma unroll
            for (int m = 1; m <= 32; m <<= 1) {
                unsigned long long o = __shfl_xor(key, m, 64);
                if (o > key) key = o;
            }
            unsigned wflat = 4095u - (unsigned)(key & 4095ull);
            r1 = __builtin_amdgcn_readfirstlane((int)(wflat >> 6));
            c1 = (int)(wflat & 63u);
        }

        // retire (r1,c1) [and (r2,c2)]
        if (lane == r1) mycol = c1;
        if (lane == c1) done  = true;
        rowmask &= ~(1ull << r1);
        retired++;
        if (two) {
            if (lane == r2) mycol = c2;
            if (lane == c2) done  = true;
            rowmask &= ~(1ull << r2);
            retired++;
        }

        // rescan affected group(s); (r>>3) is wave-uniform
        RESCAN_SWITCH(r1 >> 3)
        if (two && ((r2 >> 3) != (r1 >> 3))) {
            RESCAN_SWITCH(r2 >> 3)
        }
    }

    // ---- write hard permutation row (lane i -> row i) -----------------
    float* orow = out + (size_t)b * 4096 + lane * 64;
    #pragma unroll
    for (int t2 = 0; t2 < 16; ++t2) {
        float4 q;
        q.x = (4*t2+0 == mycol) ? 1.0f : 0.0f;
        q.y = (4*t2+1 == mycol) ? 1.0f : 0.0f;
        q.z = (4*t2+2 == mycol) ? 1.0f : 0.0f;
        q.w = (4*t2+3 == mycol) ? 1.0f : 0.0f;
        ((float4*)orow)[t2] = q;
    }
}

extern "C" void kernel_launch(void* const* d_in, const int* in_sizes, int n_in,
                              void* d_out, int out_size, void* d_ws, size_t ws_size,
                              hipStream_t stream) {
    const float* logits = (const float*)d_in[0];
    const float* ptemp  = (const float*)d_in[1];
    float* out = (float*)d_out;
    const int B = in_sizes[0] / 4096;   // 64*64 elements per batch
    sinkhorn_perm_kernel<<<(B + 1) / 2, 256, 0, stream>>>(logits, ptemp, out, B);
}